// Round 13
// baseline (474.869 us; speedup 1.0000x reference)
//
#include <hip/hip_runtime.h>
#include <hip/hip_cooperative_groups.h>
#include <cstddef>

namespace cg = cooperative_groups;

#define S_LEN 2048
#define D_MODEL 512
#define NHEAD 8
#define DH 64
#define FF_DIM 2048
#define L_TAGS 32
#define START_TAG 30
#define STOP_TAG 31
#define NEGV (-10000.0f)
#define QSCALE 0.18033688f   // 0.125 * log2(e)

typedef unsigned int uint2v __attribute__((ext_vector_type(2)));
typedef __attribute__((ext_vector_type(8))) short short8v;   // 8 bf16 = 4 VGPR
typedef __attribute__((ext_vector_type(4))) float f32x4;

union U8 { uint4 u; short8v s; };

__device__ __forceinline__ unsigned short f2bf(float f) {
  unsigned u = __float_as_uint(f);
  u += 0x7fff + ((u >> 16) & 1);   // RTNE
  return (unsigned short)(u >> 16);
}
__device__ __forceinline__ unsigned cvtpk(float lo, float hi) {
  unsigned r;
  asm("v_cvt_pk_bf16_f32 %0, %1, %2" : "=v"(r) : "v"(lo), "v"(hi));
  return r;
}

// ---------------- fused f32 -> bf16 weight converts ----------------
__global__ __launch_bounds__(256) void k_f2h4(const float* __restrict__ s0, short* __restrict__ d0,
                                              const float* __restrict__ s1, short* __restrict__ d1,
                                              const float* __restrict__ s2, short* __restrict__ d2,
                                              const float* __restrict__ s3, short* __restrict__ d3) {
  const int b = blockIdx.x;
  const float* src; short* dst; int i;
  if (b < 384)       { src = s0; dst = d0; i = b * 256 + threadIdx.x; }
  else if (b < 512)  { src = s1; dst = d1; i = (b - 384) * 256 + threadIdx.x; }
  else if (b < 1024) { src = s2; dst = d2; i = (b - 512) * 256 + threadIdx.x; }
  else               { src = s3; dst = d3; i = (b - 1024) * 256 + threadIdx.x; }
  f32x4 a = *(const f32x4*)(src + (size_t)i * 8);
  f32x4 c = *(const f32x4*)(src + (size_t)i * 8 + 4);
  U8 t;
  t.u.x = cvtpk(a[0], a[1]); t.u.y = cvtpk(a[2], a[3]);
  t.u.z = cvtpk(c[0], c[1]); t.u.w = cvtpk(c[2], c[3]);
  *(short8v*)(dst + (size_t)i * 8) = t.s;
}

// ======== QKV GEMM with fused embedding gather (XCD-chunked swizzle) ========
__global__ __launch_bounds__(256, 2) void k_gemm_qkv(const int* __restrict__ sent,
                                                     const float* __restrict__ embed,
                                                     const short* __restrict__ B,
                                                     const float* __restrict__ bias,
                                                     short* __restrict__ C,
                                                     int N, int K) {
  __shared__ __align__(16) short As[2][128 * 64];
  __shared__ __align__(16) short Bs[2][128 * 64];
  const int tid = threadIdx.x;
  const int nwg = gridDim.x * gridDim.y;
  int lin = blockIdx.x + gridDim.x * blockIdx.y;
  int wk = (lin & 7) * (nwg >> 3) + (lin >> 3);
  const int bxs = wk % gridDim.x, bys = wk / gridDim.x;
  const int bm = bys * 128, bn = bxs * 128;
  const int w = tid >> 6, lane = tid & 63;
  const int wr = w >> 1, wc = w & 1;
  const int fr = lane & 15, kg = lane >> 4;
  const int srow = tid >> 1, sc0 = (tid & 1) * 4;
  const int swz = srow & 7;
  const float* gA = embed + (size_t)sent[bm + srow] * K + sc0 * 8;
  const short* gB = B + (size_t)(bn + srow) * K + sc0 * 8;
  f32x4 ra[8];
  short8v rb[4];
  f32x4 acc[4][4] = {};

  auto loadg = [&](int k0) {
#pragma unroll
    for (int c = 0; c < 4; ++c) {
      ra[2 * c] = *(const f32x4*)(gA + k0 + c * 8);
      ra[2 * c + 1] = *(const f32x4*)(gA + k0 + c * 8 + 4);
      rb[c] = *(const short8v*)(gB + k0 + c * 8);
    }
  };
  auto storeb = [&](int b) {
    short* dA = &As[b][srow * 64];
    short* dB = &Bs[b][srow * 64];
#pragma unroll
    for (int c = 0; c < 4; ++c) {
      U8 ta;
      ta.u.x = cvtpk(ra[2 * c][0], ra[2 * c][1]);
      ta.u.y = cvtpk(ra[2 * c][2], ra[2 * c][3]);
      ta.u.z = cvtpk(ra[2 * c + 1][0], ra[2 * c + 1][1]);
      ta.u.w = cvtpk(ra[2 * c + 1][2], ra[2 * c + 1][3]);
      *(short8v*)(dA + (((sc0 + c) ^ swz) << 3)) = ta.s;
      *(short8v*)(dB + (((sc0 + c) ^ swz) << 3)) = rb[c];
    }
  };

  loadg(0);
  storeb(0);
  __syncthreads();
  int cur = 0;
  const int fswz = fr & 7;
  for (int k0 = 0; k0 < K; k0 += 64) {
    const bool more = (k0 + 64) < K;
    if (more) loadg(k0 + 64);
    const short* rA = &As[cur][(wr * 64 + fr) * 64];
    const short* rB = &Bs[cur][(wc * 64 + fr) * 64];
#pragma unroll
    for (int ks = 0; ks < 2; ++ks) {
      const int co = ((ks * 4 + kg) ^ fswz) << 3;
      short8v af[4], bf[4];
#pragma unroll
      for (int rt = 0; rt < 4; ++rt) af[rt] = *(const short8v*)(rA + rt * 16 * 64 + co);
#pragma unroll
      for (int ct = 0; ct < 4; ++ct) bf[ct] = *(const short8v*)(rB + ct * 16 * 64 + co);
#pragma unroll
      for (int rt = 0; rt < 4; ++rt)
#pragma unroll
        for (int ct = 0; ct < 4; ++ct)
          acc[rt][ct] = __builtin_amdgcn_mfma_f32_16x16x32_bf16(af[rt], bf[ct], acc[rt][ct], 0, 0, 0);
    }
    if (more) storeb(cur ^ 1);
    __syncthreads();
    cur ^= 1;
  }
#pragma unroll
  for (int rt = 0; rt < 4; ++rt) {
#pragma unroll
    for (int ct = 0; ct < 4; ++ct) {
      f32x4 v = acc[rt][ct];
      const int row0 = bm + wr * 64 + rt * 16 + kg * 4;
      const int col = bn + wc * 64 + ct * 16 + fr;
      const float bs = bias[col];
#pragma unroll
      for (int j = 0; j < 4; ++j)
        C[(size_t)(row0 + j) * N + col] = (short)f2bf(v[j] + bs);
    }
  }
}

// ======== bf16 MFMA GEMM (XCD-chunked swizzle) ========
template <int RT, bool RELU, bool OBF>
__global__ __launch_bounds__(256, 2) void k_gemm_bf(const short* __restrict__ A,
                                                    const short* __restrict__ B,
                                                    const float* __restrict__ bias,
                                                    void* __restrict__ Cp,
                                                    int M, int N, int K) {
  constexpr int BM = RT * 32;
  constexpr int CH = (BM * 8) / 256;
  __shared__ __align__(16) short As[2][BM * 64];
  __shared__ __align__(16) short Bs[2][BM * 64];
  const int tid = threadIdx.x;
  const int nwg = gridDim.x * gridDim.y;
  int lin = blockIdx.x + gridDim.x * blockIdx.y;
  int wk = (lin & 7) * (nwg >> 3) + (lin >> 3);
  const int bxs = wk % gridDim.x, bys = wk / gridDim.x;
  const int bm = bys * BM, bn = bxs * BM;
  const int w = tid >> 6, lane = tid & 63;
  const int wr = w >> 1, wc = w & 1;
  const int fr = lane & 15, kg = lane >> 4;
  const int srow = (RT == 4) ? (tid >> 1) : (tid >> 2);
  const int sc0 = (RT == 4) ? ((tid & 1) * 4) : ((tid & 3) * 2);
  const int swz = srow & 7;
  const short* gA = A + (size_t)(bm + srow) * K + sc0 * 8;
  const short* gB = B + (size_t)(bn + srow) * K + sc0 * 8;
  short8v ra[CH], rb[CH];
  f32x4 acc[RT][RT] = {};

  auto loadg = [&](int k0) {
#pragma unroll
    for (int c = 0; c < CH; ++c) {
      ra[c] = *(const short8v*)(gA + k0 + c * 8);
      rb[c] = *(const short8v*)(gB + k0 + c * 8);
    }
  };
  auto storeb = [&](int b) {
    short* dA = &As[b][srow * 64];
    short* dB = &Bs[b][srow * 64];
#pragma unroll
    for (int c = 0; c < CH; ++c) {
      *(short8v*)(dA + (((sc0 + c) ^ swz) << 3)) = ra[c];
      *(short8v*)(dB + (((sc0 + c) ^ swz) << 3)) = rb[c];
    }
  };

  loadg(0);
  storeb(0);
  __syncthreads();
  int cur = 0;
  const int fswz = fr & 7;
  for (int k0 = 0; k0 < K; k0 += 64) {
    const bool more = (k0 + 64) < K;
    if (more) loadg(k0 + 64);
    const short* rA = &As[cur][(wr * (RT * 16) + fr) * 64];
    const short* rB = &Bs[cur][(wc * (RT * 16) + fr) * 64];
#pragma unroll
    for (int ks = 0; ks < 2; ++ks) {
      const int co = ((ks * 4 + kg) ^ fswz) << 3;
      short8v af[RT], bf[RT];
#pragma unroll
      for (int rt = 0; rt < RT; ++rt) af[rt] = *(const short8v*)(rA + rt * 16 * 64 + co);
#pragma unroll
      for (int ct = 0; ct < RT; ++ct) bf[ct] = *(const short8v*)(rB + ct * 16 * 64 + co);
#pragma unroll
      for (int rt = 0; rt < RT; ++rt)
#pragma unroll
        for (int ct = 0; ct < RT; ++ct)
          acc[rt][ct] = __builtin_amdgcn_mfma_f32_16x16x32_bf16(af[rt], bf[ct], acc[rt][ct], 0, 0, 0);
    }
    if (more) storeb(cur ^ 1);
    __syncthreads();
    cur ^= 1;
  }
#pragma unroll
  for (int rt = 0; rt < RT; ++rt) {
#pragma unroll
    for (int ct = 0; ct < RT; ++ct) {
      f32x4 v = acc[rt][ct];
      const int row0 = bm + wr * (RT * 16) + rt * 16 + kg * 4;
      const int col = bn + wc * (RT * 16) + ct * 16 + fr;
      const float bs = bias[col];
#pragma unroll
      for (int j = 0; j < 4; ++j) {
        float o = v[j] + bs;
        if (RELU) o = fmaxf(o, 0.f);
        if (OBF)
          ((short*)Cp)[(size_t)(row0 + j) * N + col] = (short)f2bf(o);
        else
          ((float*)Cp)[(size_t)(row0 + j) * N + col] = o;
      }
    }
  }
}

// ======== fused attention v6: exp2 softmax + lazy l-reduction ========
__global__ __launch_bounds__(256) void k_attn(const short* __restrict__ qkv,
                                              short* __restrict__ ob) {
  __shared__ __align__(16) short Ks[2][64 * 64];
  __shared__ __align__(16) short Vt[2][64 * 72];
  __shared__ __align__(16) short Pl[4][16 * 72];
  const int tid = threadIdx.x;
  const int b = blockIdx.x;
  const int h = b & 7;
  const int bq = (b >> 3) * 64;
  const int wq = tid >> 6, lane = tid & 63;
  const int fr = lane & 15, kg = lane >> 4;
  auto scale8 = [](short8v q) -> short8v {
    unsigned wv[4];
#pragma unroll
    for (int i = 0; i < 4; ++i) {
      float lo = __uint_as_float(((unsigned)(unsigned short)q[2 * i]) << 16) * QSCALE;
      float hi = __uint_as_float(((unsigned)(unsigned short)q[2 * i + 1]) << 16) * QSCALE;
      wv[i] = cvtpk(lo, hi);
    }
    U8 t;
    t.u.x = wv[0]; t.u.y = wv[1]; t.u.z = wv[2]; t.u.w = wv[3];
    return t.s;
  };
  short8v qf[2];
  {
    const short* qsrc = qkv + (size_t)(bq + wq * 16 + fr) * 1536 + h * DH;
    qf[0] = scale8(*(const short8v*)(qsrc + kg * 8));
    qf[1] = scale8(*(const short8v*)(qsrc + 32 + kg * 8));
  }
  float m[4], ls[4];
  f32x4 oac[4] = {};
#pragma unroll
  for (int j = 0; j < 4; ++j) { m[j] = -1e30f; ls[j] = 0.f; }

  const int srow = tid >> 2, sc0 = (tid & 3) * 2;
  const int kpair = tid & 31, dgrp = tid >> 5;
  short8v kr0, kr1, va, vb;
  auto loadt = [&](int kt) {
    const short* kbase = qkv + (size_t)(kt * 64 + srow) * 1536 + 512 + h * DH;
    kr0 = *(const short8v*)(kbase + sc0 * 8);
    kr1 = *(const short8v*)(kbase + sc0 * 8 + 8);
    const short* vbase = qkv + (size_t)(kt * 64 + 2 * kpair) * 1536 + 1024 + h * DH + dgrp * 8;
    va = *(const short8v*)(vbase);
    vb = *(const short8v*)(vbase + 1536);
  };
  auto storet = [&](int cu) {
    short* dk = &Ks[cu][srow * 64];
    *(short8v*)(dk + ((sc0 ^ (srow & 7)) << 3)) = kr0;
    *(short8v*)(dk + (((sc0 + 1) ^ (srow & 7)) << 3)) = kr1;
#pragma unroll
    for (int i = 0; i < 8; ++i) {
      unsigned u = ((unsigned)(unsigned short)va[i]) |
                   (((unsigned)(unsigned short)vb[i]) << 16);
      *(unsigned*)&Vt[cu][(dgrp * 8 + i) * 72 + 2 * kpair] = u;
    }
  };

  loadt(0);
  int cur = 0;
  for (int kt = 0; kt < 32; ++kt) {
    storet(cur);
    __syncthreads();
    if (kt < 31) loadt(kt + 1);
    f32x4 sac[4] = {};
#pragma unroll
    for (int ks = 0; ks < 2; ++ks) {
#pragma unroll
      for (int ct = 0; ct < 4; ++ct) {
        const int row = ct * 16 + fr;
        short8v bfr = *(const short8v*)&Ks[cur][row * 64 + (((ks * 4 + kg) ^ (row & 7)) << 3)];
        sac[ct] = __builtin_amdgcn_mfma_f32_16x16x32_bf16(qf[ks], bfr, sac[ct], 0, 0, 0);
      }
    }
    // online softmax in log2 units; l kept as lane-local partial (reduced once at end)
    float pv[4][4];
#pragma unroll
    for (int j = 0; j < 4; ++j) {
      float v = fmaxf(fmaxf(sac[0][j], sac[1][j]), fmaxf(sac[2][j], sac[3][j]));
#pragma unroll
      for (int off = 1; off < 16; off <<= 1) v = fmaxf(v, __shfl_xor(v, off, 64));
      float mn = fmaxf(m[j], v);
      float f = __builtin_amdgcn_exp2f(m[j] - mn);
      m[j] = mn;
      float rs = 0.f;
#pragma unroll
      for (int ct = 0; ct < 4; ++ct) {
        pv[ct][j] = __builtin_amdgcn_exp2f(sac[ct][j] - mn);
        rs += pv[ct][j];
      }
      ls[j] = ls[j] * f + rs;   // lane-local partial (4 columns' worth)
#pragma unroll
      for (int ct = 0; ct < 4; ++ct) oac[ct][j] *= f;
    }
#pragma unroll
    for (int ct = 0; ct < 4; ++ct)
#pragma unroll
      for (int j = 0; j < 4; ++j)
        Pl[wq][(kg * 4 + j) * 72 + ct * 16 + fr] = (short)f2bf(pv[ct][j]);
#pragma unroll
    for (int ks = 0; ks < 2; ++ks) {
      short8v paf = *(const short8v*)&Pl[wq][fr * 72 + ks * 32 + kg * 8];
#pragma unroll
      for (int ct = 0; ct < 4; ++ct) {
        short8v vf = *(const short8v*)&Vt[cur][(ct * 16 + fr) * 72 + ks * 32 + kg * 8];
        oac[ct] = __builtin_amdgcn_mfma_f32_16x16x32_bf16(paf, vf, oac[ct], 0, 0, 0);
      }
    }
    cur ^= 1;
  }
#pragma unroll
  for (int j = 0; j < 4; ++j) {
#pragma unroll
    for (int off = 1; off < 16; off <<= 1) ls[j] += __shfl_xor(ls[j], off, 64);
    float inv = 1.f / ls[j];
    const int q = bq + wq * 16 + kg * 4 + j;
#pragma unroll
    for (int ct = 0; ct < 4; ++ct)
      ob[(size_t)q * D_MODEL + h * DH + ct * 16 + fr] = (short)f2bf(oac[ct][j] * inv);
  }
}

// ---------------- residual + layernorm (ln1: gathered residual, dual output) ----------------
__global__ __launch_bounds__(128) void k_ln(const float* __restrict__ a,
                                            const int* __restrict__ sent,
                                            const float* __restrict__ embed,
                                            const float* __restrict__ r,
                                            const float* __restrict__ g,
                                            const float* __restrict__ b,
                                            float* __restrict__ out,
                                            short* __restrict__ outh) {
  __shared__ float red[2];
  const int row = blockIdx.x, tid = threadIdx.x;
  const size_t off = (size_t)row * D_MODEL + tid * 4;
  float4 av;
  if (sent)
    av = *(const float4*)(embed + (size_t)sent[row] * D_MODEL + tid * 4);
  else
    av = *(const float4*)(a + off);
  float4 rv = *(const float4*)(r + off);
  float v0 = av.x + rv.x, v1 = av.y + rv.y, v2 = av.z + rv.z, v3 = av.w + rv.w;
  float s = v0 + v1 + v2 + v3;
#pragma unroll
  for (int d = 1; d < 64; d <<= 1) s += __shfl_xor(s, d, 64);
  if ((tid & 63) == 0) red[tid >> 6] = s;
  __syncthreads();
  float mean = (red[0] + red[1]) * (1.f / 512.f);
  __syncthreads();
  float d0 = v0 - mean, d1 = v1 - mean, d2 = v2 - mean, d3 = v3 - mean;
  float sq = d0 * d0 + d1 * d1 + d2 * d2 + d3 * d3;
#pragma unroll
  for (int d = 1; d < 64; d <<= 1) sq += __shfl_xor(sq, d, 64);
  if ((tid & 63) == 0) red[tid >> 6] = sq;
  __syncthreads();
  float inv = rsqrtf((red[0] + red[1]) * (1.f / 512.f) + 1e-5f);
  float4 gv = *(const float4*)(g + tid * 4);
  float4 bv = *(const float4*)(b + tid * 4);
  float4 o;
  o.x = d0 * inv * gv.x + bv.x;
  o.y = d1 * inv * gv.y + bv.y;
  o.z = d2 * inv * gv.z + bv.z;
  o.w = d3 * inv * gv.w + bv.w;
  *(float4*)(out + off) = o;
  if (outh) {
    uint2v t;
    t[0] = cvtpk(o.x, o.y);
    t[1] = cvtpk(o.z, o.w);
    *(uint2v*)(outh + off) = t;
  }
}

// ---------------- FUSED ln2 + emission ----------------
__global__ __launch_bounds__(128) void k_lnfeats(const float* __restrict__ a,
                                                 const float* __restrict__ r,
                                                 const float* __restrict__ g,
                                                 const float* __restrict__ b,
                                                 const float* __restrict__ Wt,
                                                 const float* __restrict__ bt,
                                                 float* __restrict__ feats) {
  __shared__ float red[2];
  __shared__ float part[2][32];
  const int row = blockIdx.x, tid = threadIdx.x;
  const size_t off = (size_t)row * D_MODEL + tid * 4;
  float4 av = *(const float4*)(a + off);
  float4 rv = *(const float4*)(r + off);
  float v0 = av.x + rv.x, v1 = av.y + rv.y, v2 = av.z + rv.z, v3 = av.w + rv.w;
  float s = v0 + v1 + v2 + v3;
#pragma unroll
  for (int d = 1; d < 64; d <<= 1) s += __shfl_xor(s, d, 64);
  if ((tid & 63) == 0) red[tid >> 6] = s;
  __syncthreads();
  float mean = (red[0] + red[1]) * (1.f / 512.f);
  __syncthreads();
  float d0 = v0 - mean, d1 = v1 - mean, d2 = v2 - mean, d3 = v3 - mean;
  float sq = d0 * d0 + d1 * d1 + d2 * d2 + d3 * d3;
#pragma unroll
  for (int d = 1; d < 64; d <<= 1) sq += __shfl_xor(sq, d, 64);
  if ((tid & 63) == 0) red[tid >> 6] = sq;
  __syncthreads();
  float inv = rsqrtf((red[0] + red[1]) * (1.f / 512.f) + 1e-5f);
  float4 gv = *(const float4*)(g + tid * 4);
  float4 bv = *(const float4*)(b + tid * 4);
  float4 o;
  o.x = d0 * inv * gv.x + bv.x;
  o.y = d1 * inv * gv.y + bv.y;
  o.z = d2 * inv * gv.z + bv.z;
  o.w = d3 * inv * gv.w + bv.w;
  const int lane = tid & 63, wv = tid >> 6;
#pragma unroll
  for (int l = 0; l < 32; ++l) {
    float4 wr4 = *(const float4*)(Wt + (size_t)l * D_MODEL + tid * 4);
    float p = o.x * wr4.x + o.y * wr4.y + o.z * wr4.z + o.w * wr4.w;
#pragma unroll
    for (int d = 1; d < 64; d <<= 1) p += __shfl_xor(p, d, 64);
    if (lane == 0) part[wv][l] = p;
  }
  __syncthreads();
  if (tid < 32) feats[(size_t)row * L_TAGS + tid] = part[0][tid] + part[1][tid] + bt[tid];
}

// ============ FUSED cooperative Viterbi: scan1+scan2+scan3+trace ============
// grid 1024 x 64. Phase1: all blocks (chunk products). Phase2: block 0
// (boundary chain + terminal). Phase3: blocks 0..63 (alphas+bp+cand walk).
// Phase4: block 0 (compose + emit path).
__global__ __launch_bounds__(64) void k_viterbi(const float* __restrict__ feats,
                                                const float* __restrict__ T,
                                                float* __restrict__ P,
                                                float* __restrict__ alphas,
                                                float* __restrict__ out,
                                                int* __restrict__ bestp,
                                                unsigned char* __restrict__ cand,
                                                unsigned char* __restrict__ amap) {
  __shared__ float S[2][32];
  __shared__ float Sa[32];
  __shared__ unsigned char bpl[32][32];
  __shared__ unsigned cnd[256];
  __shared__ unsigned char Am[64][32];
  __shared__ unsigned char et[64];
  cg::grid_group grid = cg::this_grid();
  const int blk = blockIdx.x;
  const int l = threadIdx.x, n = l & 31, half = l >> 5;

  // ---- phase 1: chunk products (all 1024 blocks; c = blk>>4, col pair blk&15) ----
  {
    const int c = blk >> 4;
    const int pl = half;
    const int p = (blk & 15) * 2 + pl;
    float Trow[32];
#pragma unroll
    for (int q = 0; q < 32; ++q) Trow[q] = T[n * 32 + q];
    const int tbase = c * 32;
    float er[4];
#pragma unroll
    for (int i = 0; i < 4; ++i) er[i] = feats[(tbase + i) * 32 + n];
    float a = T[n * 32 + p] + er[0];
    S[pl][n] = a;
    const float* fp = feats + (size_t)(tbase + 4) * 32 + n;
    er[0] = fp[0]; fp += 32;
    for (int u = 1; u < 32; ++u) {
      float e = er[u & 3];
      float enew = fp[0]; fp += 32;
      const float4* Sv = (const float4*)&S[pl][0];
      float g[32];
#pragma unroll
      for (int j4 = 0; j4 < 8; ++j4) {
        float4 sv = Sv[j4];
        g[j4 * 4 + 0] = sv.x + Trow[j4 * 4 + 0];
        g[j4 * 4 + 1] = sv.y + Trow[j4 * 4 + 1];
        g[j4 * 4 + 2] = sv.z + Trow[j4 * 4 + 2];
        g[j4 * 4 + 3] = sv.w + Trow[j4 * 4 + 3];
      }
#pragma unroll
      for (int st = 1; st < 32; st <<= 1)
#pragma unroll
        for (int j = 0; j < 32; j += 2 * st) g[j] = fmaxf(g[j], g[j + st]);
      a = g[0] + e;
      S[pl][n] = a;
      er[u & 3] = enew;
    }
    P[(size_t)c * 1024 + n * 32 + p] = a;
  }
  grid.sync();

  // ---- phase 2: boundary chain + terminal (block 0) ----
  if (blk == 0) {
    float a = (n == START_TAG) ? 0.f : NEGV;
    const float* pbase = P + n * 32 + half * 16;
    float4 pr[4];
#pragma unroll
    for (int j = 0; j < 4; ++j) pr[j] = *(const float4*)(pbase + j * 4);
    for (int c = 0; c < 64; ++c) {
      float4 nx[4];
#pragma unroll
      for (int j = 0; j < 4; ++j)
        nx[j] = *(const float4*)(pbase + (size_t)(c + 1) * 1024 + j * 4);
      alphas[(size_t)(c * 32) * 32 + n] = a;
      Sa[n] = a;
      const float4* Sv = (const float4*)&Sa[half * 16];
      float g[16];
#pragma unroll
      for (int j = 0; j < 4; ++j) {
        float4 sv = Sv[j];
        g[j * 4 + 0] = pr[j].x + sv.x;
        g[j * 4 + 1] = pr[j].y + sv.y;
        g[j * 4 + 2] = pr[j].z + sv.z;
        g[j * 4 + 3] = pr[j].w + sv.w;
      }
#pragma unroll
      for (int st = 1; st < 16; st <<= 1)
#pragma unroll
        for (int j = 0; j < 16; j += 2 * st) g[j] = fmaxf(g[j], g[j + st]);
      uint2v r = __builtin_amdgcn_permlane32_swap(__float_as_uint(g[0]),
                                                  __float_as_uint(g[0]), false, false);
      a = fmaxf(__uint_as_float(r[0]), __uint_as_float(r[1]));
#pragma unroll
      for (int j = 0; j < 4; ++j) pr[j] = nx[j];
    }
    float term = a + T[STOP_TAG * 32 + n];
    float bv = term;
    int bi = n;
#pragma unroll
    for (int d = 1; d < 32; d <<= 1) {
      float ov = __shfl_xor(bv, d, 64);
      int oi = __shfl_xor(bi, d, 64);
      if (ov > bv || (ov == bv && oi < bi)) { bv = ov; bi = oi; }
    }
    if (l == 0) { out[0] = bv; *bestp = bi; }
  }
  grid.sync();

  // ---- phase 3: alphas + backpointers + candidate walk (blocks 0..63) ----
  if (blk < 64) {
    const int c = blk;
    float Tr[16];
#pragma unroll
    for (int j = 0; j < 16; ++j) Tr[j] = T[n * 32 + half * 16 + j];
    const int tbase = c * 32;
    float a = alphas[(size_t)tbase * 32 + n];
    float er[4];
#pragma unroll
    for (int i = 0; i < 4; ++i) er[i] = feats[(tbase + i) * 32 + n];
    const float* fp = feats + (size_t)(tbase + 4) * 32 + n;
    Sa[n] = a;
    for (int u = 0; u < 32; ++u) {
      float e = er[u & 3];
      float enew = fp[0]; fp += 32;
      const float4* Sv = (const float4*)&Sa[half * 16];
      float4 s0 = Sv[0], s1 = Sv[1], s2 = Sv[2], s3 = Sv[3];
      float v[16] = {s0.x + Tr[0],  s0.y + Tr[1],  s0.z + Tr[2],  s0.w + Tr[3],
                     s1.x + Tr[4],  s1.y + Tr[5],  s1.z + Tr[6],  s1.w + Tr[7],
                     s2.x + Tr[8],  s2.y + Tr[9],  s2.z + Tr[10], s2.w + Tr[11],
                     s3.x + Tr[12], s3.y + Tr[13], s3.z + Tr[14], s3.w + Tr[15]};
      int id[16];
#pragma unroll
      for (int j = 0; j < 16; ++j) id[j] = half * 16 + j;
#pragma unroll
      for (int st = 1; st < 16; st <<= 1)
#pragma unroll
        for (int j = 0; j < 16; j += 2 * st)
          if (v[j + st] > v[j]) { v[j] = v[j + st]; id[j] = id[j + st]; }
      uint2v rv = __builtin_amdgcn_permlane32_swap(__float_as_uint(v[0]),
                                                   __float_as_uint(v[0]), false, false);
      uint2v ri = __builtin_amdgcn_permlane32_swap((unsigned)id[0], (unsigned)id[0],
                                                   false, false);
      float v0 = __uint_as_float(rv[0]), v1 = __uint_as_float(rv[1]);
      int i0 = (int)ri[0], i1 = (int)ri[1];
      float wvv = (v1 > v0) ? v1 : v0;
      int wi = (v1 > v0) ? i1 : i0;
      bpl[u][n] = (unsigned char)wi;
      a = wvv + e;
      Sa[n] = a;
      er[u & 3] = enew;
    }
    unsigned char* cnb = (unsigned char*)cnd;
    int tg = n;
    cnb[n * 32 + 31] = (unsigned char)n;
    for (int j = 31; j >= 1; --j) {
      tg = bpl[j][tg];
      cnb[n * 32 + (j - 1)] = (unsigned char)tg;
    }
    if (half == 0) amap[c * 32 + n] = bpl[0][tg];
#pragma unroll
    for (int i = 0; i < 4; ++i)
      ((unsigned*)(cand + (size_t)c * 1024))[l * 4 + i] = cnd[l * 4 + i];
  }
  grid.sync();

  // ---- phase 4: compose chunk maps + emit path (block 0, 64 threads) ----
  if (blk == 0) {
#pragma unroll
    for (int i = 0; i < 8; ++i)
      ((unsigned*)&Am[0][0])[l + 64 * i] = ((const unsigned*)amap)[l + 64 * i];
    __syncthreads();
    for (int d = 1; d < 64; d <<= 1) {
      unsigned char tmpv[32];
#pragma unroll
      for (int i = 0; i < 32; ++i) {
        int id = l + 64 * i;
        int cc = id >> 5, e = id & 31;
        tmpv[i] = (cc + d < 64) ? Am[cc][Am[cc + d][e]] : Am[cc][e];
      }
      __syncthreads();
#pragma unroll
      for (int i = 0; i < 32; ++i) {
        int id = l + 64 * i;
        Am[id >> 5][id & 31] = tmpv[i];
      }
      __syncthreads();
    }
    const int best = *bestp;
    et[l] = (l == 63) ? (unsigned char)best : Am[l + 1][best];
    __syncthreads();
#pragma unroll
    for (int i = 0; i < 32; ++i) {
      int t = l + 64 * i;
      int cc = t >> 5, j = t & 31;
      out[1 + t] = (float)cand[(size_t)cc * 1024 + (size_t)et[cc] * 32 + j];
    }
  }
}

extern "C" void kernel_launch(void* const* d_in, const int* in_sizes, int n_in,
                              void* d_out, int out_size, void* d_ws, size_t ws_size,
                              hipStream_t stream) {
  (void)in_sizes; (void)n_in; (void)out_size; (void)ws_size;
  const int* sent = (const int*)d_in[0];
  const float* embed = (const float*)d_in[1];
  const float* Wqkv = (const float*)d_in[2];
  const float* bqkv = (const float*)d_in[3];
  const float* Wo = (const float*)d_in[4];
  const float* bo = (const float*)d_in[5];
  const float* g1 = (const float*)d_in[6];
  const float* b1n = (const float*)d_in[7];
  const float* W1 = (const float*)d_in[8];
  const float* b1f = (const float*)d_in[9];
  const float* W2 = (const float*)d_in[10];
  const float* b2f = (const float*)d_in[11];
  const float* g2 = (const float*)d_in[12];
  const float* b2n = (const float*)d_in[13];
  const float* Wt = (const float*)d_in[14];
  const float* bt = (const float*)d_in[15];
  const float* T = (const float*)d_in[16];
  float* out = (float*)d_out;

  float* ws = (float*)d_ws;
  const size_t M1 = 1u << 20;  // 1M floats = 4MB
  short* qkvh = (short*)ws;                 // bf16 [2048][1536]
  short* obh = (short*)(ws + 2 * M1);       // bf16 [2048][512]
  float* yb = ws + 3 * M1;                  // f32  [2048][512]
  float* x1 = ws + 4 * M1;                  // f32
  short* x1h = (short*)(ws + 5 * M1);       // bf16
  short* ffbh = (short*)(ws + 6 * M1);      // bf16 [2048][2048]
  float* zb = ws + 8 * M1;                  // f32
  short* wqkvh = (short*)(ws + 10 * M1);
  short* woh = wqkvh + 786432;
  short* w1h = woh + 262144;
  short* w2h = w1h + 1048576;
  float* feats = ws + 11 * M1;
  float* alphas = feats + 2048 * 32 + 64;
  float* P = alphas + 2049 * 32 + 64;
  int* bestp = (int*)(P + 65 * 1024 + 64);
  unsigned char* cand = (unsigned char*)(bestp + 64);
  unsigned char* amap = cand + 2048 * 32;

  k_f2h4<<<dim3(1536), dim3(256), 0, stream>>>(Wqkv, wqkvh, Wo, woh, W1, w1h, W2, w2h);
  k_gemm_qkv<<<dim3(12, 16), dim3(256), 0, stream>>>(sent, embed, wqkvh, bqkv, qkvh, 1536, 512);
  k_attn<<<dim3(256), dim3(256), 0, stream>>>(qkvh, obh);
  k_gemm_bf<2, false, false><<<dim3(8, 32), dim3(256), 0, stream>>>(obh, woh, bo, yb, 2048, 512, 512);
  k_ln<<<dim3(2048), dim3(128), 0, stream>>>(nullptr, sent, embed, yb, g1, b1n, x1, x1h);
  k_gemm_bf<4, true, true><<<dim3(16, 16), dim3(256), 0, stream>>>(x1h, w1h, b1f, ffbh, 2048, 2048, 512);
  k_gemm_bf<2, false, false><<<dim3(8, 32), dim3(256), 0, stream>>>(ffbh, w2h, b2f, zb, 2048, 512, 2048);
  k_lnfeats<<<dim3(2048), dim3(128), 0, stream>>>(x1, zb, g2, b2n, Wt, bt, feats);
  {
    void* args[] = {(void*)&feats, (void*)&T, (void*)&P, (void*)&alphas,
                    (void*)&out, (void*)&bestp, (void*)&cand, (void*)&amap};
    hipLaunchCooperativeKernel((void*)k_viterbi, dim3(1024), dim3(64), args, 0, stream);
  }
}

// Round 14
// 179.063 us; speedup vs baseline: 2.6520x; 2.6520x over previous
//
#include <hip/hip_runtime.h>
#include <cstddef>

#define S_LEN 2048
#define D_MODEL 512
#define NHEAD 8
#define DH 64
#define FF_DIM 2048
#define L_TAGS 32
#define START_TAG 30
#define STOP_TAG 31
#define NEGV (-10000.0f)
#define QSCALE 0.18033688f   // 0.125 * log2(e)

typedef unsigned int uint2v __attribute__((ext_vector_type(2)));
typedef __attribute__((ext_vector_type(8))) short short8v;   // 8 bf16 = 4 VGPR
typedef __attribute__((ext_vector_type(4))) float f32x4;

union U8 { uint4 u; short8v s; };

__device__ __forceinline__ unsigned short f2bf(float f) {
  unsigned u = __float_as_uint(f);
  u += 0x7fff + ((u >> 16) & 1);   // RTNE
  return (unsigned short)(u >> 16);
}
__device__ __forceinline__ unsigned cvtpk(float lo, float hi) {
  unsigned r;
  asm("v_cvt_pk_bf16_f32 %0, %1, %2" : "=v"(r) : "v"(lo), "v"(hi));
  return r;
}

// ---------------- fused f32 -> bf16 weight converts ----------------
__global__ __launch_bounds__(256) void k_f2h4(const float* __restrict__ s0, short* __restrict__ d0,
                                              const float* __restrict__ s1, short* __restrict__ d1,
                                              const float* __restrict__ s2, short* __restrict__ d2,
                                              const float* __restrict__ s3, short* __restrict__ d3) {
  const int b = blockIdx.x;
  const float* src; short* dst; int i;
  if (b < 384)       { src = s0; dst = d0; i = b * 256 + threadIdx.x; }
  else if (b < 512)  { src = s1; dst = d1; i = (b - 384) * 256 + threadIdx.x; }
  else if (b < 1024) { src = s2; dst = d2; i = (b - 512) * 256 + threadIdx.x; }
  else               { src = s3; dst = d3; i = (b - 1024) * 256 + threadIdx.x; }
  f32x4 a = *(const f32x4*)(src + (size_t)i * 8);
  f32x4 c = *(const f32x4*)(src + (size_t)i * 8 + 4);
  U8 t;
  t.u.x = cvtpk(a[0], a[1]); t.u.y = cvtpk(a[2], a[3]);
  t.u.z = cvtpk(c[0], c[1]); t.u.w = cvtpk(c[2], c[3]);
  *(short8v*)(dst + (size_t)i * 8) = t.s;
}

// ======== QKV GEMM with fused embedding gather (XCD-chunked swizzle) ========
__global__ __launch_bounds__(256, 2) void k_gemm_qkv(const int* __restrict__ sent,
                                                     const float* __restrict__ embed,
                                                     const short* __restrict__ B,
                                                     const float* __restrict__ bias,
                                                     short* __restrict__ C,
                                                     int N, int K) {
  __shared__ __align__(16) short As[2][128 * 64];
  __shared__ __align__(16) short Bs[2][128 * 64];
  const int tid = threadIdx.x;
  const int nwg = gridDim.x * gridDim.y;
  int lin = blockIdx.x + gridDim.x * blockIdx.y;
  int wk = (lin & 7) * (nwg >> 3) + (lin >> 3);
  const int bxs = wk % gridDim.x, bys = wk / gridDim.x;
  const int bm = bys * 128, bn = bxs * 128;
  const int w = tid >> 6, lane = tid & 63;
  const int wr = w >> 1, wc = w & 1;
  const int fr = lane & 15, kg = lane >> 4;
  const int srow = tid >> 1, sc0 = (tid & 1) * 4;
  const int swz = srow & 7;
  const float* gA = embed + (size_t)sent[bm + srow] * K + sc0 * 8;
  const short* gB = B + (size_t)(bn + srow) * K + sc0 * 8;
  f32x4 ra[8];
  short8v rb[4];
  f32x4 acc[4][4] = {};

  auto loadg = [&](int k0) {
#pragma unroll
    for (int c = 0; c < 4; ++c) {
      ra[2 * c] = *(const f32x4*)(gA + k0 + c * 8);
      ra[2 * c + 1] = *(const f32x4*)(gA + k0 + c * 8 + 4);
      rb[c] = *(const short8v*)(gB + k0 + c * 8);
    }
  };
  auto storeb = [&](int b) {
    short* dA = &As[b][srow * 64];
    short* dB = &Bs[b][srow * 64];
#pragma unroll
    for (int c = 0; c < 4; ++c) {
      U8 ta;
      ta.u.x = cvtpk(ra[2 * c][0], ra[2 * c][1]);
      ta.u.y = cvtpk(ra[2 * c][2], ra[2 * c][3]);
      ta.u.z = cvtpk(ra[2 * c + 1][0], ra[2 * c + 1][1]);
      ta.u.w = cvtpk(ra[2 * c + 1][2], ra[2 * c + 1][3]);
      *(short8v*)(dA + (((sc0 + c) ^ swz) << 3)) = ta.s;
      *(short8v*)(dB + (((sc0 + c) ^ swz) << 3)) = rb[c];
    }
  };

  loadg(0);
  storeb(0);
  __syncthreads();
  int cur = 0;
  const int fswz = fr & 7;
  for (int k0 = 0; k0 < K; k0 += 64) {
    const bool more = (k0 + 64) < K;
    if (more) loadg(k0 + 64);
    const short* rA = &As[cur][(wr * 64 + fr) * 64];
    const short* rB = &Bs[cur][(wc * 64 + fr) * 64];
#pragma unroll
    for (int ks = 0; ks < 2; ++ks) {
      const int co = ((ks * 4 + kg) ^ fswz) << 3;
      short8v af[4], bf[4];
#pragma unroll
      for (int rt = 0; rt < 4; ++rt) af[rt] = *(const short8v*)(rA + rt * 16 * 64 + co);
#pragma unroll
      for (int ct = 0; ct < 4; ++ct) bf[ct] = *(const short8v*)(rB + ct * 16 * 64 + co);
#pragma unroll
      for (int rt = 0; rt < 4; ++rt)
#pragma unroll
        for (int ct = 0; ct < 4; ++ct)
          acc[rt][ct] = __builtin_amdgcn_mfma_f32_16x16x32_bf16(af[rt], bf[ct], acc[rt][ct], 0, 0, 0);
    }
    if (more) storeb(cur ^ 1);
    __syncthreads();
    cur ^= 1;
  }
#pragma unroll
  for (int rt = 0; rt < 4; ++rt) {
#pragma unroll
    for (int ct = 0; ct < 4; ++ct) {
      f32x4 v = acc[rt][ct];
      const int row0 = bm + wr * 64 + rt * 16 + kg * 4;
      const int col = bn + wc * 64 + ct * 16 + fr;
      const float bs = bias[col];
#pragma unroll
      for (int j = 0; j < 4; ++j)
        C[(size_t)(row0 + j) * N + col] = (short)f2bf(v[j] + bs);
    }
  }
}

// ======== bf16 MFMA GEMM (XCD-chunked swizzle) ========
template <int RT, bool RELU, bool OBF>
__global__ __launch_bounds__(256, 2) void k_gemm_bf(const short* __restrict__ A,
                                                    const short* __restrict__ B,
                                                    const float* __restrict__ bias,
                                                    void* __restrict__ Cp,
                                                    int M, int N, int K) {
  constexpr int BM = RT * 32;
  constexpr int CH = (BM * 8) / 256;
  __shared__ __align__(16) short As[2][BM * 64];
  __shared__ __align__(16) short Bs[2][BM * 64];
  const int tid = threadIdx.x;
  const int nwg = gridDim.x * gridDim.y;
  int lin = blockIdx.x + gridDim.x * blockIdx.y;
  int wk = (lin & 7) * (nwg >> 3) + (lin >> 3);
  const int bxs = wk % gridDim.x, bys = wk / gridDim.x;
  const int bm = bys * BM, bn = bxs * BM;
  const int w = tid >> 6, lane = tid & 63;
  const int wr = w >> 1, wc = w & 1;
  const int fr = lane & 15, kg = lane >> 4;
  const int srow = (RT == 4) ? (tid >> 1) : (tid >> 2);
  const int sc0 = (RT == 4) ? ((tid & 1) * 4) : ((tid & 3) * 2);
  const int swz = srow & 7;
  const short* gA = A + (size_t)(bm + srow) * K + sc0 * 8;
  const short* gB = B + (size_t)(bn + srow) * K + sc0 * 8;
  short8v ra[CH], rb[CH];
  f32x4 acc[RT][RT] = {};

  auto loadg = [&](int k0) {
#pragma unroll
    for (int c = 0; c < CH; ++c) {
      ra[c] = *(const short8v*)(gA + k0 + c * 8);
      rb[c] = *(const short8v*)(gB + k0 + c * 8);
    }
  };
  auto storeb = [&](int b) {
    short* dA = &As[b][srow * 64];
    short* dB = &Bs[b][srow * 64];
#pragma unroll
    for (int c = 0; c < CH; ++c) {
      *(short8v*)(dA + (((sc0 + c) ^ swz) << 3)) = ra[c];
      *(short8v*)(dB + (((sc0 + c) ^ swz) << 3)) = rb[c];
    }
  };

  loadg(0);
  storeb(0);
  __syncthreads();
  int cur = 0;
  const int fswz = fr & 7;
  for (int k0 = 0; k0 < K; k0 += 64) {
    const bool more = (k0 + 64) < K;
    if (more) loadg(k0 + 64);
    const short* rA = &As[cur][(wr * (RT * 16) + fr) * 64];
    const short* rB = &Bs[cur][(wc * (RT * 16) + fr) * 64];
#pragma unroll
    for (int ks = 0; ks < 2; ++ks) {
      const int co = ((ks * 4 + kg) ^ fswz) << 3;
      short8v af[RT], bf[RT];
#pragma unroll
      for (int rt = 0; rt < RT; ++rt) af[rt] = *(const short8v*)(rA + rt * 16 * 64 + co);
#pragma unroll
      for (int ct = 0; ct < RT; ++ct) bf[ct] = *(const short8v*)(rB + ct * 16 * 64 + co);
#pragma unroll
      for (int rt = 0; rt < RT; ++rt)
#pragma unroll
        for (int ct = 0; ct < RT; ++ct)
          acc[rt][ct] = __builtin_amdgcn_mfma_f32_16x16x32_bf16(af[rt], bf[ct], acc[rt][ct], 0, 0, 0);
    }
    if (more) storeb(cur ^ 1);
    __syncthreads();
    cur ^= 1;
  }
#pragma unroll
  for (int rt = 0; rt < RT; ++rt) {
#pragma unroll
    for (int ct = 0; ct < RT; ++ct) {
      f32x4 v = acc[rt][ct];
      const int row0 = bm + wr * (RT * 16) + rt * 16 + kg * 4;
      const int col = bn + wc * (RT * 16) + ct * 16 + fr;
      const float bs = bias[col];
#pragma unroll
      for (int j = 0; j < 4; ++j) {
        float o = v[j] + bs;
        if (RELU) o = fmaxf(o, 0.f);
        if (OBF)
          ((short*)Cp)[(size_t)(row0 + j) * N + col] = (short)f2bf(o);
        else
          ((float*)Cp)[(size_t)(row0 + j) * N + col] = o;
      }
    }
  }
}

// ======== fused attention v6: exp2 softmax + lazy l-reduction ========
__global__ __launch_bounds__(256) void k_attn(const short* __restrict__ qkv,
                                              short* __restrict__ ob) {
  __shared__ __align__(16) short Ks[2][64 * 64];
  __shared__ __align__(16) short Vt[2][64 * 72];
  __shared__ __align__(16) short Pl[4][16 * 72];
  const int tid = threadIdx.x;
  const int b = blockIdx.x;
  const int h = b & 7;
  const int bq = (b >> 3) * 64;
  const int wq = tid >> 6, lane = tid & 63;
  const int fr = lane & 15, kg = lane >> 4;
  auto scale8 = [](short8v q) -> short8v {
    unsigned wv[4];
#pragma unroll
    for (int i = 0; i < 4; ++i) {
      float lo = __uint_as_float(((unsigned)(unsigned short)q[2 * i]) << 16) * QSCALE;
      float hi = __uint_as_float(((unsigned)(unsigned short)q[2 * i + 1]) << 16) * QSCALE;
      wv[i] = cvtpk(lo, hi);
    }
    U8 t;
    t.u.x = wv[0]; t.u.y = wv[1]; t.u.z = wv[2]; t.u.w = wv[3];
    return t.s;
  };
  short8v qf[2];
  {
    const short* qsrc = qkv + (size_t)(bq + wq * 16 + fr) * 1536 + h * DH;
    qf[0] = scale8(*(const short8v*)(qsrc + kg * 8));
    qf[1] = scale8(*(const short8v*)(qsrc + 32 + kg * 8));
  }
  float m[4], ls[4];
  f32x4 oac[4] = {};
#pragma unroll
  for (int j = 0; j < 4; ++j) { m[j] = -1e30f; ls[j] = 0.f; }

  const int srow = tid >> 2, sc0 = (tid & 3) * 2;
  const int kpair = tid & 31, dgrp = tid >> 5;
  short8v kr0, kr1, va, vb;
  auto loadt = [&](int kt) {
    const short* kbase = qkv + (size_t)(kt * 64 + srow) * 1536 + 512 + h * DH;
    kr0 = *(const short8v*)(kbase + sc0 * 8);
    kr1 = *(const short8v*)(kbase + sc0 * 8 + 8);
    const short* vbase = qkv + (size_t)(kt * 64 + 2 * kpair) * 1536 + 1024 + h * DH + dgrp * 8;
    va = *(const short8v*)(vbase);
    vb = *(const short8v*)(vbase + 1536);
  };
  auto storet = [&](int cu) {
    short* dk = &Ks[cu][srow * 64];
    *(short8v*)(dk + ((sc0 ^ (srow & 7)) << 3)) = kr0;
    *(short8v*)(dk + (((sc0 + 1) ^ (srow & 7)) << 3)) = kr1;
#pragma unroll
    for (int i = 0; i < 8; ++i) {
      unsigned u = ((unsigned)(unsigned short)va[i]) |
                   (((unsigned)(unsigned short)vb[i]) << 16);
      *(unsigned*)&Vt[cu][(dgrp * 8 + i) * 72 + 2 * kpair] = u;
    }
  };

  loadt(0);
  int cur = 0;
  for (int kt = 0; kt < 32; ++kt) {
    storet(cur);
    __syncthreads();
    if (kt < 31) loadt(kt + 1);
    f32x4 sac[4] = {};
#pragma unroll
    for (int ks = 0; ks < 2; ++ks) {
#pragma unroll
      for (int ct = 0; ct < 4; ++ct) {
        const int row = ct * 16 + fr;
        short8v bfr = *(const short8v*)&Ks[cur][row * 64 + (((ks * 4 + kg) ^ (row & 7)) << 3)];
        sac[ct] = __builtin_amdgcn_mfma_f32_16x16x32_bf16(qf[ks], bfr, sac[ct], 0, 0, 0);
      }
    }
    float pv[4][4];
#pragma unroll
    for (int j = 0; j < 4; ++j) {
      float v = fmaxf(fmaxf(sac[0][j], sac[1][j]), fmaxf(sac[2][j], sac[3][j]));
#pragma unroll
      for (int off = 1; off < 16; off <<= 1) v = fmaxf(v, __shfl_xor(v, off, 64));
      float mn = fmaxf(m[j], v);
      float f = __builtin_amdgcn_exp2f(m[j] - mn);
      m[j] = mn;
      float rs = 0.f;
#pragma unroll
      for (int ct = 0; ct < 4; ++ct) {
        pv[ct][j] = __builtin_amdgcn_exp2f(sac[ct][j] - mn);
        rs += pv[ct][j];
      }
      ls[j] = ls[j] * f + rs;   // lane-local partial; reduced once in epilogue
#pragma unroll
      for (int ct = 0; ct < 4; ++ct) oac[ct][j] *= f;
    }
#pragma unroll
    for (int ct = 0; ct < 4; ++ct)
#pragma unroll
      for (int j = 0; j < 4; ++j)
        Pl[wq][(kg * 4 + j) * 72 + ct * 16 + fr] = (short)f2bf(pv[ct][j]);
#pragma unroll
    for (int ks = 0; ks < 2; ++ks) {
      short8v paf = *(const short8v*)&Pl[wq][fr * 72 + ks * 32 + kg * 8];
#pragma unroll
      for (int ct = 0; ct < 4; ++ct) {
        short8v vf = *(const short8v*)&Vt[cur][(ct * 16 + fr) * 72 + ks * 32 + kg * 8];
        oac[ct] = __builtin_amdgcn_mfma_f32_16x16x32_bf16(paf, vf, oac[ct], 0, 0, 0);
      }
    }
    cur ^= 1;
  }
#pragma unroll
  for (int j = 0; j < 4; ++j) {
#pragma unroll
    for (int off = 1; off < 16; off <<= 1) ls[j] += __shfl_xor(ls[j], off, 64);
    float inv = 1.f / ls[j];
    const int q = bq + wq * 16 + kg * 4 + j;
#pragma unroll
    for (int ct = 0; ct < 4; ++ct)
      ob[(size_t)q * D_MODEL + h * DH + ct * 16 + fr] = (short)f2bf(oac[ct][j] * inv);
  }
}

// ---------------- residual + layernorm (ln1: gathered residual, dual output) ----------------
__global__ __launch_bounds__(128) void k_ln(const float* __restrict__ a,
                                            const int* __restrict__ sent,
                                            const float* __restrict__ embed,
                                            const float* __restrict__ r,
                                            const float* __restrict__ g,
                                            const float* __restrict__ b,
                                            float* __restrict__ out,
                                            short* __restrict__ outh) {
  __shared__ float red[2];
  const int row = blockIdx.x, tid = threadIdx.x;
  const size_t off = (size_t)row * D_MODEL + tid * 4;
  float4 av;
  if (sent)
    av = *(const float4*)(embed + (size_t)sent[row] * D_MODEL + tid * 4);
  else
    av = *(const float4*)(a + off);
  float4 rv = *(const float4*)(r + off);
  float v0 = av.x + rv.x, v1 = av.y + rv.y, v2 = av.z + rv.z, v3 = av.w + rv.w;
  float s = v0 + v1 + v2 + v3;
#pragma unroll
  for (int d = 1; d < 64; d <<= 1) s += __shfl_xor(s, d, 64);
  if ((tid & 63) == 0) red[tid >> 6] = s;
  __syncthreads();
  float mean = (red[0] + red[1]) * (1.f / 512.f);
  __syncthreads();
  float d0 = v0 - mean, d1 = v1 - mean, d2 = v2 - mean, d3 = v3 - mean;
  float sq = d0 * d0 + d1 * d1 + d2 * d2 + d3 * d3;
#pragma unroll
  for (int d = 1; d < 64; d <<= 1) sq += __shfl_xor(sq, d, 64);
  if ((tid & 63) == 0) red[tid >> 6] = sq;
  __syncthreads();
  float inv = rsqrtf((red[0] + red[1]) * (1.f / 512.f) + 1e-5f);
  float4 gv = *(const float4*)(g + tid * 4);
  float4 bv = *(const float4*)(b + tid * 4);
  float4 o;
  o.x = d0 * inv * gv.x + bv.x;
  o.y = d1 * inv * gv.y + bv.y;
  o.z = d2 * inv * gv.z + bv.z;
  o.w = d3 * inv * gv.w + bv.w;
  *(float4*)(out + off) = o;
  if (outh) {
    uint2v t;
    t[0] = cvtpk(o.x, o.y);
    t[1] = cvtpk(o.z, o.w);
    *(uint2v*)(outh + off) = t;
  }
}

// ---------------- FUSED ln2 + emission ----------------
__global__ __launch_bounds__(128) void k_lnfeats(const float* __restrict__ a,
                                                 const float* __restrict__ r,
                                                 const float* __restrict__ g,
                                                 const float* __restrict__ b,
                                                 const float* __restrict__ Wt,
                                                 const float* __restrict__ bt,
                                                 float* __restrict__ feats) {
  __shared__ float red[2];
  __shared__ float part[2][32];
  const int row = blockIdx.x, tid = threadIdx.x;
  const size_t off = (size_t)row * D_MODEL + tid * 4;
  float4 av = *(const float4*)(a + off);
  float4 rv = *(const float4*)(r + off);
  float v0 = av.x + rv.x, v1 = av.y + rv.y, v2 = av.z + rv.z, v3 = av.w + rv.w;
  float s = v0 + v1 + v2 + v3;
#pragma unroll
  for (int d = 1; d < 64; d <<= 1) s += __shfl_xor(s, d, 64);
  if ((tid & 63) == 0) red[tid >> 6] = s;
  __syncthreads();
  float mean = (red[0] + red[1]) * (1.f / 512.f);
  __syncthreads();
  float d0 = v0 - mean, d1 = v1 - mean, d2 = v2 - mean, d3 = v3 - mean;
  float sq = d0 * d0 + d1 * d1 + d2 * d2 + d3 * d3;
#pragma unroll
  for (int d = 1; d < 64; d <<= 1) sq += __shfl_xor(sq, d, 64);
  if ((tid & 63) == 0) red[tid >> 6] = sq;
  __syncthreads();
  float inv = rsqrtf((red[0] + red[1]) * (1.f / 512.f) + 1e-5f);
  float4 gv = *(const float4*)(g + tid * 4);
  float4 bv = *(const float4*)(b + tid * 4);
  float4 o;
  o.x = d0 * inv * gv.x + bv.x;
  o.y = d1 * inv * gv.y + bv.y;
  o.z = d2 * inv * gv.z + bv.z;
  o.w = d3 * inv * gv.w + bv.w;
  const int lane = tid & 63, wv = tid >> 6;
#pragma unroll
  for (int l = 0; l < 32; ++l) {
    float4 wr4 = *(const float4*)(Wt + (size_t)l * D_MODEL + tid * 4);
    float p = o.x * wr4.x + o.y * wr4.y + o.z * wr4.z + o.w * wr4.w;
#pragma unroll
    for (int d = 1; d < 64; d <<= 1) p += __shfl_xor(p, d, 64);
    if (lane == 0) part[wv][l] = p;
  }
  __syncthreads();
  if (tid < 32) feats[(size_t)row * L_TAGS + tid] = part[0][tid] + part[1][tid] + bt[tid];
}

// ============ Viterbi via chunked max-plus scan (4 plain launches) ============
__global__ __launch_bounds__(64) void k_scan1(const float* __restrict__ feats,
                                              const float* __restrict__ T,
                                              float* __restrict__ P) {
  __shared__ float S[2][32];
  const int c = blockIdx.x >> 4;
  const int l = threadIdx.x;
  const int n = l & 31, pl = l >> 5;
  const int p = (blockIdx.x & 15) * 2 + pl;
  float Trow[32];
#pragma unroll
  for (int q = 0; q < 32; ++q) Trow[q] = T[n * 32 + q];
  const int tbase = c * 32;
  float er[4];
#pragma unroll
  for (int i = 0; i < 4; ++i) er[i] = feats[(tbase + i) * 32 + n];
  float a = T[n * 32 + p] + er[0];
  S[pl][n] = a;
  const float* fp = feats + (size_t)(tbase + 4) * 32 + n;
  er[0] = fp[0]; fp += 32;
  for (int u = 1; u < 32; ++u) {
    float e = er[u & 3];
    float enew = fp[0]; fp += 32;
    const float4* Sv = (const float4*)&S[pl][0];
    float g[32];
#pragma unroll
    for (int j4 = 0; j4 < 8; ++j4) {
      float4 sv = Sv[j4];
      g[j4 * 4 + 0] = sv.x + Trow[j4 * 4 + 0];
      g[j4 * 4 + 1] = sv.y + Trow[j4 * 4 + 1];
      g[j4 * 4 + 2] = sv.z + Trow[j4 * 4 + 2];
      g[j4 * 4 + 3] = sv.w + Trow[j4 * 4 + 3];
    }
#pragma unroll
    for (int st = 1; st < 32; st <<= 1)
#pragma unroll
      for (int j = 0; j < 32; j += 2 * st) g[j] = fmaxf(g[j], g[j + st]);
    a = g[0] + e;
    S[pl][n] = a;
    er[u & 3] = enew;
  }
  P[(size_t)c * 1024 + n * 32 + p] = a;
}

__global__ __launch_bounds__(64) void k_scan2(const float* __restrict__ P,
                                              const float* __restrict__ T,
                                              float* __restrict__ alphas,
                                              float* __restrict__ out,
                                              int* __restrict__ bestp) {
  __shared__ float Sa[32];
  const int l = threadIdx.x, n = l & 31, half = l >> 5;
  float a = (n == START_TAG) ? 0.f : NEGV;
  const float* pbase = P + n * 32 + half * 16;
  float4 pr[4];
#pragma unroll
  for (int j = 0; j < 4; ++j) pr[j] = *(const float4*)(pbase + j * 4);
  for (int c = 0; c < 64; ++c) {
    float4 nx[4];
#pragma unroll
    for (int j = 0; j < 4; ++j)
      nx[j] = *(const float4*)(pbase + (size_t)(c + 1) * 1024 + j * 4);
    alphas[(size_t)(c * 32) * 32 + n] = a;
    Sa[n] = a;
    const float4* Sv = (const float4*)&Sa[half * 16];
    float g[16];
#pragma unroll
    for (int j = 0; j < 4; ++j) {
      float4 sv = Sv[j];
      g[j * 4 + 0] = pr[j].x + sv.x;
      g[j * 4 + 1] = pr[j].y + sv.y;
      g[j * 4 + 2] = pr[j].z + sv.z;
      g[j * 4 + 3] = pr[j].w + sv.w;
    }
#pragma unroll
    for (int st = 1; st < 16; st <<= 1)
#pragma unroll
      for (int j = 0; j < 16; j += 2 * st) g[j] = fmaxf(g[j], g[j + st]);
    uint2v r = __builtin_amdgcn_permlane32_swap(__float_as_uint(g[0]),
                                                __float_as_uint(g[0]), false, false);
    a = fmaxf(__uint_as_float(r[0]), __uint_as_float(r[1]));
#pragma unroll
    for (int j = 0; j < 4; ++j) pr[j] = nx[j];
  }
  float term = a + T[STOP_TAG * 32 + n];
  float bv = term;
  int bi = n;
#pragma unroll
  for (int d = 1; d < 32; d <<= 1) {
    float ov = __shfl_xor(bv, d, 64);
    int oi = __shfl_xor(bi, d, 64);
    if (ov > bv || (ov == bv && oi < bi)) { bv = ov; bi = oi; }
  }
  if (l == 0) { out[0] = bv; *bestp = bi; }
}

// phase 3 FUSED: per-chunk alphas + backpointers + candidate walk.
__global__ __launch_bounds__(64) void k_scan3(const float* __restrict__ feats,
                                              const float* __restrict__ T,
                                              const float* __restrict__ alphas,
                                              unsigned char* __restrict__ cand,
                                              unsigned char* __restrict__ amap) {
  __shared__ float Sa[32];
  __shared__ unsigned char bpl[32][32];
  __shared__ unsigned cnd[256];
  const int c = blockIdx.x, l = threadIdx.x, n = l & 31, half = l >> 5;
  float Tr[16];
#pragma unroll
  for (int j = 0; j < 16; ++j) Tr[j] = T[n * 32 + half * 16 + j];
  const int tbase = c * 32;
  float a = alphas[(size_t)tbase * 32 + n];
  float er[4];
#pragma unroll
  for (int i = 0; i < 4; ++i) er[i] = feats[(tbase + i) * 32 + n];
  const float* fp = feats + (size_t)(tbase + 4) * 32 + n;
  Sa[n] = a;
  for (int u = 0; u < 32; ++u) {
    float e = er[u & 3];
    float enew = fp[0]; fp += 32;
    const float4* Sv = (const float4*)&Sa[half * 16];
    float4 s0 = Sv[0], s1 = Sv[1], s2 = Sv[2], s3 = Sv[3];
    float v[16] = {s0.x + Tr[0],  s0.y + Tr[1],  s0.z + Tr[2],  s0.w + Tr[3],
                   s1.x + Tr[4],  s1.y + Tr[5],  s1.z + Tr[6],  s1.w + Tr[7],
                   s2.x + Tr[8],  s2.y + Tr[9],  s2.z + Tr[10], s2.w + Tr[11],
                   s3.x + Tr[12], s3.y + Tr[13], s3.z + Tr[14], s3.w + Tr[15]};
    int id[16];
#pragma unroll
    for (int j = 0; j < 16; ++j) id[j] = half * 16 + j;
#pragma unroll
    for (int st = 1; st < 16; st <<= 1)
#pragma unroll
      for (int j = 0; j < 16; j += 2 * st)
        if (v[j + st] > v[j]) { v[j] = v[j + st]; id[j] = id[j + st]; }
    uint2v rv = __builtin_amdgcn_permlane32_swap(__float_as_uint(v[0]),
                                                 __float_as_uint(v[0]), false, false);
    uint2v ri = __builtin_amdgcn_permlane32_swap((unsigned)id[0], (unsigned)id[0],
                                                 false, false);
    float v0 = __uint_as_float(rv[0]), v1 = __uint_as_float(rv[1]);
    int i0 = (int)ri[0], i1 = (int)ri[1];
    float wvv = (v1 > v0) ? v1 : v0;
    int wi = (v1 > v0) ? i1 : i0;
    bpl[u][n] = (unsigned char)wi;
    a = wvv + e;
    Sa[n] = a;
    er[u & 3] = enew;
  }
  unsigned char* cnb = (unsigned char*)cnd;
  int tg = n;
  cnb[n * 32 + 31] = (unsigned char)n;
  for (int j = 31; j >= 1; --j) {
    tg = bpl[j][tg];
    cnb[n * 32 + (j - 1)] = (unsigned char)tg;
  }
  if (half == 0) amap[c * 32 + n] = bpl[0][tg];
#pragma unroll
  for (int i = 0; i < 4; ++i)
    ((unsigned*)(cand + (size_t)c * 1024))[l * 4 + i] = cnd[l * 4 + i];
}

// traceback: compose chunk maps + emit path.
__global__ __launch_bounds__(256) void k_trace2(const unsigned char* __restrict__ amap,
                                                const unsigned char* __restrict__ cand,
                                                const int* __restrict__ bestp,
                                                float* __restrict__ outp) {
  __shared__ unsigned char Am[64][32];
  __shared__ unsigned char et[64];
  const int tid = threadIdx.x;
  ((unsigned*)&Am[0][0])[tid] = ((const unsigned*)amap)[tid];
  ((unsigned*)&Am[32][0])[tid] = ((const unsigned*)amap)[tid + 256];
  __syncthreads();
  for (int d = 1; d < 64; d <<= 1) {
    unsigned char tmpv[8];
#pragma unroll
    for (int i = 0; i < 8; ++i) {
      int id = tid + 256 * i;
      int cc = id >> 5, e = id & 31;
      tmpv[i] = (cc + d < 64) ? Am[cc][Am[cc + d][e]] : Am[cc][e];
    }
    __syncthreads();
#pragma unroll
    for (int i = 0; i < 8; ++i) {
      int id = tid + 256 * i;
      Am[id >> 5][id & 31] = tmpv[i];
    }
    __syncthreads();
  }
  const int best = *bestp;
  if (tid < 64) et[tid] = (tid == 63) ? (unsigned char)best : Am[tid + 1][best];
  __syncthreads();
#pragma unroll
  for (int i = 0; i < 8; ++i) {
    int t = tid + 256 * i;
    int cc = t >> 5, j = t & 31;
    outp[1 + t] = (float)cand[(size_t)cc * 1024 + (size_t)et[cc] * 32 + j];
  }
}

extern "C" void kernel_launch(void* const* d_in, const int* in_sizes, int n_in,
                              void* d_out, int out_size, void* d_ws, size_t ws_size,
                              hipStream_t stream) {
  (void)in_sizes; (void)n_in; (void)out_size; (void)ws_size;
  const int* sent = (const int*)d_in[0];
  const float* embed = (const float*)d_in[1];
  const float* Wqkv = (const float*)d_in[2];
  const float* bqkv = (const float*)d_in[3];
  const float* Wo = (const float*)d_in[4];
  const float* bo = (const float*)d_in[5];
  const float* g1 = (const float*)d_in[6];
  const float* b1n = (const float*)d_in[7];
  const float* W1 = (const float*)d_in[8];
  const float* b1f = (const float*)d_in[9];
  const float* W2 = (const float*)d_in[10];
  const float* b2f = (const float*)d_in[11];
  const float* g2 = (const float*)d_in[12];
  const float* b2n = (const float*)d_in[13];
  const float* Wt = (const float*)d_in[14];
  const float* bt = (const float*)d_in[15];
  const float* T = (const float*)d_in[16];
  float* out = (float*)d_out;

  float* ws = (float*)d_ws;
  const size_t M1 = 1u << 20;  // 1M floats = 4MB
  short* qkvh = (short*)ws;                 // bf16 [2048][1536]
  short* obh = (short*)(ws + 2 * M1);       // bf16 [2048][512]
  float* yb = ws + 3 * M1;                  // f32  [2048][512]
  float* x1 = ws + 4 * M1;                  // f32
  short* x1h = (short*)(ws + 5 * M1);       // bf16
  short* ffbh = (short*)(ws + 6 * M1);      // bf16 [2048][2048]
  float* zb = ws + 8 * M1;                  // f32
  short* wqkvh = (short*)(ws + 10 * M1);
  short* woh = wqkvh + 786432;
  short* w1h = woh + 262144;
  short* w2h = w1h + 1048576;
  float* feats = ws + 11 * M1;
  float* alphas = feats + 2048 * 32 + 64;
  float* P = alphas + 2049 * 32 + 64;
  int* bestp = (int*)(P + 65 * 1024 + 64);
  unsigned char* cand = (unsigned char*)(bestp + 64);
  unsigned char* amap = cand + 2048 * 32;

  k_f2h4<<<dim3(1536), dim3(256), 0, stream>>>(Wqkv, wqkvh, Wo, woh, W1, w1h, W2, w2h);
  k_gemm_qkv<<<dim3(12, 16), dim3(256), 0, stream>>>(sent, embed, wqkvh, bqkv, qkvh, 1536, 512);
  k_attn<<<dim3(256), dim3(256), 0, stream>>>(qkvh, obh);
  k_gemm_bf<2, false, false><<<dim3(8, 32), dim3(256), 0, stream>>>(obh, woh, bo, yb, 2048, 512, 512);
  k_ln<<<dim3(2048), dim3(128), 0, stream>>>(nullptr, sent, embed, yb, g1, b1n, x1, x1h);
  k_gemm_bf<4, true, true><<<dim3(16, 16), dim3(256), 0, stream>>>(x1h, w1h, b1f, ffbh, 2048, 2048, 512);
  k_gemm_bf<2, false, false><<<dim3(8, 32), dim3(256), 0, stream>>>(ffbh, w2h, b2f, zb, 2048, 512, 2048);
  k_lnfeats<<<dim3(2048), dim3(128), 0, stream>>>(x1, zb, g2, b2n, Wt, bt, feats);
  k_scan1<<<dim3(1024), dim3(64), 0, stream>>>(feats, T, P);
  k_scan2<<<dim3(1), dim3(64), 0, stream>>>(P, T, alphas, out, bestp);
  k_scan3<<<dim3(64), dim3(64), 0, stream>>>(feats, T, alphas, cand, amap);
  k_trace2<<<dim3(1), dim3(256), 0, stream>>>(amap, cand, bestp, out);
}